// Round 4
// baseline (2079.726 us; speedup 1.0000x reference)
//
#include <hip/hip_runtime.h>
#include <math.h>

#define BB 256
#define TT 2048
#define FF 2
#define HH 128
#define OO 2
#define NT 768   // 12 waves: 3 gates x 2 column-halves x 2 waves(128 threads)

__device__ __forceinline__ float fast_rcp(float x) { return __builtin_amdgcn_rcpf(x); }
__device__ __forceinline__ float sigmoid_f(float x) { return fast_rcp(1.0f + __expf(-x)); }
__device__ __forceinline__ float tanh_f(float x) { return 1.0f - 2.0f * fast_rcp(1.0f + __expf(2.0f * x)); }

// ---- 64 named scalar weights: never an array, never address-taken ----
#define FORW(M) \
  M(0)  M(1)  M(2)  M(3)  M(4)  M(5)  M(6)  M(7)  \
  M(8)  M(9)  M(10) M(11) M(12) M(13) M(14) M(15) \
  M(16) M(17) M(18) M(19) M(20) M(21) M(22) M(23) \
  M(24) M(25) M(26) M(27) M(28) M(29) M(30) M(31) \
  M(32) M(33) M(34) M(35) M(36) M(37) M(38) M(39) \
  M(40) M(41) M(42) M(43) M(44) M(45) M(46) M(47) \
  M(48) M(49) M(50) M(51) M(52) M(53) M(54) M(55) \
  M(56) M(57) M(58) M(59) M(60) M(61) M(62) M(63)

#define DECLW(i) float w_##i;
#define LOADW(i) w_##i = Wcol[(c64 + i) * HH];

#define DOTB(q, ia, ib, ic, id)                    \
    {                                              \
        const float4 h4_ = hp[q];                  \
        a0 = fmaf(h4_.x, w_##ia, a0);              \
        a1 = fmaf(h4_.y, w_##ib, a1);              \
        a2 = fmaf(h4_.z, w_##ic, a2);              \
        a3 = fmaf(h4_.w, w_##id, a3);              \
    }

__global__ __launch_bounds__(NT, 3)
void gru_persistent(const float* __restrict__ x, const float* __restrict__ h0,
                    const float* __restrict__ Wir, const float* __restrict__ Wiz,
                    const float* __restrict__ Win, const float* __restrict__ Whr,
                    const float* __restrict__ Whz, const float* __restrict__ Whn,
                    const float* __restrict__ bhr, const float* __restrict__ bhz,
                    const float* __restrict__ bhn, const float* __restrict__ Wd,
                    const float* __restrict__ bd, float* __restrict__ out)
{
    // out layout: [carry B*H][y B*T*O]
    __shared__ float x_sh[TT * FF];                 // 16 KB
    __shared__ __align__(16) float h_sh[HH];
    __shared__ float part[3][2][HH];                // gate x half x j partials

    const int b    = blockIdx.x;
    const int tid  = threadIdx.x;
    const int g    = tid >> 8;          // 0:r 1:z 2:n   (4 waves per gate)
    const int c    = (tid >> 7) & 1;    // column half   (2 waves per half)
    const int j    = tid & (HH - 1);    // output column
    const int wv   = tid >> 6;          // wave id 0..11
    const int lane = tid & 63;
    const int c64  = c * 64;

    const float* Wh = (g == 0) ? Whr : (g == 1) ? Whz : Whn;
    const float* Wi = (g == 0) ? Wir : (g == 1) ? Wiz : Win;
    const float* bh = (g == 0) ? bhr : (g == 1) ? bhz : bhn;

    // half weight column in 64 NAMED scalar registers
    FORW(DECLW)
    {
        const float* Wcol = Wh + j;     // column j, row stride HH
        FORW(LOADW)
    }
    // pin: asm def on plain floats -> remat/demotion impossible past here
    asm volatile("" : "+v"(w_0),  "+v"(w_1),  "+v"(w_2),  "+v"(w_3),
                      "+v"(w_4),  "+v"(w_5),  "+v"(w_6),  "+v"(w_7),
                      "+v"(w_8),  "+v"(w_9),  "+v"(w_10), "+v"(w_11),
                      "+v"(w_12), "+v"(w_13), "+v"(w_14), "+v"(w_15));
    asm volatile("" : "+v"(w_16), "+v"(w_17), "+v"(w_18), "+v"(w_19),
                      "+v"(w_20), "+v"(w_21), "+v"(w_22), "+v"(w_23),
                      "+v"(w_24), "+v"(w_25), "+v"(w_26), "+v"(w_27),
                      "+v"(w_28), "+v"(w_29), "+v"(w_30), "+v"(w_31));
    asm volatile("" : "+v"(w_32), "+v"(w_33), "+v"(w_34), "+v"(w_35),
                      "+v"(w_36), "+v"(w_37), "+v"(w_38), "+v"(w_39),
                      "+v"(w_40), "+v"(w_41), "+v"(w_42), "+v"(w_43),
                      "+v"(w_44), "+v"(w_45), "+v"(w_46), "+v"(w_47));
    asm volatile("" : "+v"(w_48), "+v"(w_49), "+v"(w_50), "+v"(w_51),
                      "+v"(w_52), "+v"(w_53), "+v"(w_54), "+v"(w_55),
                      "+v"(w_56), "+v"(w_57), "+v"(w_58), "+v"(w_59),
                      "+v"(w_60), "+v"(w_61), "+v"(w_62), "+v"(w_63));

    const float gbias = (c == 0) ? bh[j] : 0.0f;
    float wi0 = 0.0f, wi1 = 0.0f;
    if (c == 0 && g != 2) { wi0 = Wi[0 * HH + j]; wi1 = Wi[1 * HH + j]; }

    // combine-thread extras (tid < 128)
    float win0 = 0.0f, win1 = 0.0f;
    if (tid < HH) { win0 = Win[0 * HH + j]; win1 = Win[1 * HH + j]; }

    // y-wave (wave 8) extras: Wd columns for this lane's two h entries
    float wdA0 = 0.f, wdA1 = 0.f, wdB0 = 0.f, wdB1 = 0.f;
    if (wv == 8) {
        wdA0 = Wd[lane * OO + 0];        wdA1 = Wd[lane * OO + 1];
        wdB0 = Wd[(lane + 64) * OO + 0]; wdB1 = Wd[(lane + 64) * OO + 1];
    }
    const float bd0 = bd[0], bd1 = bd[1];

    // stage x row (float4) and h0
    {
        const float4* xi = reinterpret_cast<const float4*>(x + (size_t)b * TT * FF);
        float4* xo = reinterpret_cast<float4*>(x_sh);
        for (int i = tid; i < TT * FF / 4; i += NT) xo[i] = xi[i];
    }
    if (tid < HH) h_sh[tid] = h0[b * HH + tid];
    __syncthreads();

    float* __restrict__ yout = out + BB * HH;

    for (int t = 0; t < TT; ++t) {
        const float x0 = x_sh[t * FF + 0];
        const float x1 = x_sh[t * FF + 1];

        // ---- phase 1: per-gate half-column GEMV (all 768 threads) ----
        float a0 = gbias + x0 * wi0 + x1 * wi1;   // wi==0 where not applicable
        float a1 = 0.f, a2 = 0.f, a3 = 0.f;
        const float4* hp = reinterpret_cast<const float4*>(h_sh + c64);
        DOTB(0,  0,  1,  2,  3)
        DOTB(1,  4,  5,  6,  7)
        DOTB(2,  8,  9,  10, 11)
        DOTB(3,  12, 13, 14, 15)
        DOTB(4,  16, 17, 18, 19)
        DOTB(5,  20, 21, 22, 23)
        DOTB(6,  24, 25, 26, 27)
        DOTB(7,  28, 29, 30, 31)
        DOTB(8,  32, 33, 34, 35)
        DOTB(9,  36, 37, 38, 39)
        DOTB(10, 40, 41, 42, 43)
        DOTB(11, 44, 45, 46, 47)
        DOTB(12, 48, 49, 50, 51)
        DOTB(13, 52, 53, 54, 55)
        DOTB(14, 56, 57, 58, 59)
        DOTB(15, 60, 61, 62, 63)
        part[g][c][j] = (a0 + a1) + (a2 + a3);

        // wave 8 additionally emits y[t-1] from h_sh (read-only in phase 1)
        if (wv == 8 && t > 0) {
            const float hv0 = h_sh[lane], hv1 = h_sh[lane + 64];
            float p0 = hv0 * wdA0 + hv1 * wdB0;
            float p1 = hv0 * wdA1 + hv1 * wdB1;
            #pragma unroll
            for (int off = 32; off >= 1; off >>= 1) {
                p0 += __shfl_xor(p0, off);
                p1 += __shfl_xor(p1, off);
            }
            if (lane == 0)
                reinterpret_cast<float2*>(yout)[(size_t)b * TT + (t - 1)] =
                    make_float2(p0 + bd0, p1 + bd1);
        }
        __syncthreads();   // barrier A: partials visible

        // ---- phase 2: combine (threads 0..127) ----
        if (tid < HH) {
            const float racc = part[0][0][j] + part[0][1][j];
            const float zacc = part[1][0][j] + part[1][1][j];
            const float macc = part[2][0][j] + part[2][1][j];
            const float r  = sigmoid_f(racc);
            const float z  = sigmoid_f(zacc);
            const float n  = tanh_f(x0 * win0 + x1 * win1 + r * macc);
            h_sh[j] = (1.0f - z) * n + z * h_sh[j];
        }
        __syncthreads();   // barrier B: h_new visible
    }

    // tail: y[T-1] and carry
    if (wv == 8) {
        const float hv0 = h_sh[lane], hv1 = h_sh[lane + 64];
        float p0 = hv0 * wdA0 + hv1 * wdB0;
        float p1 = hv0 * wdA1 + hv1 * wdB1;
        #pragma unroll
        for (int off = 32; off >= 1; off >>= 1) {
            p0 += __shfl_xor(p0, off);
            p1 += __shfl_xor(p1, off);
        }
        if (lane == 0)
            reinterpret_cast<float2*>(yout)[(size_t)b * TT + (TT - 1)] =
                make_float2(p0 + bd0, p1 + bd1);
    }
    if (tid < HH) out[b * HH + tid] = h_sh[tid];
}

extern "C" void kernel_launch(void* const* d_in, const int* in_sizes, int n_in,
                              void* d_out, int out_size, void* d_ws, size_t ws_size,
                              hipStream_t stream) {
    const float* x   = (const float*)d_in[0];
    const float* h0  = (const float*)d_in[1];
    const float* Wir = (const float*)d_in[2];
    const float* Wiz = (const float*)d_in[3];
    const float* Win = (const float*)d_in[4];
    const float* Whr = (const float*)d_in[5];
    const float* Whz = (const float*)d_in[6];
    const float* Whn = (const float*)d_in[7];
    const float* bhr = (const float*)d_in[8];
    const float* bhz = (const float*)d_in[9];
    const float* bhn = (const float*)d_in[10];
    const float* Wd  = (const float*)d_in[11];
    const float* bd  = (const float*)d_in[12];
    float* out = (float*)d_out;

    gru_persistent<<<BB, NT, 0, stream>>>(x, h0, Wir, Wiz, Win, Whr, Whz, Whn,
                                          bhr, bhz, bhn, Wd, bd, out);
}

// Round 5
// 2079.167 us; speedup vs baseline: 1.0003x; 1.0003x over previous
//
#include <hip/hip_runtime.h>
#include <math.h>

#define BB 256
#define TT 2048
#define FF 2
#define HH 128
#define OO 2
#define NT 768   // 12 waves: 3 gates x 2 column-halves x 2 waves(128 threads)

__device__ __forceinline__ float fast_rcp(float x) { return __builtin_amdgcn_rcpf(x); }
__device__ __forceinline__ float sigmoid_f(float x) { return fast_rcp(1.0f + __expf(-x)); }
__device__ __forceinline__ float tanh_f(float x) { return 1.0f - 2.0f * fast_rcp(1.0f + __expf(2.0f * x)); }

// ---- 64 named scalar weights: never an array, never address-taken ----
#define FORW(M) \
  M(0)  M(1)  M(2)  M(3)  M(4)  M(5)  M(6)  M(7)  \
  M(8)  M(9)  M(10) M(11) M(12) M(13) M(14) M(15) \
  M(16) M(17) M(18) M(19) M(20) M(21) M(22) M(23) \
  M(24) M(25) M(26) M(27) M(28) M(29) M(30) M(31) \
  M(32) M(33) M(34) M(35) M(36) M(37) M(38) M(39) \
  M(40) M(41) M(42) M(43) M(44) M(45) M(46) M(47) \
  M(48) M(49) M(50) M(51) M(52) M(53) M(54) M(55) \
  M(56) M(57) M(58) M(59) M(60) M(61) M(62) M(63)

#define DECLW(i) float w_##i;
#define LOADW(i) w_##i = Wcol[(c64 + i) * HH];

#define DOTB(q, ia, ib, ic, id)                    \
    {                                              \
        const float4 h4_ = hp[q];                  \
        a0 = fmaf(h4_.x, w_##ia, a0);              \
        a1 = fmaf(h4_.y, w_##ib, a1);              \
        a2 = fmaf(h4_.z, w_##ic, a2);              \
        a3 = fmaf(h4_.w, w_##id, a3);              \
    }

__global__ __launch_bounds__(NT, 1) __attribute__((amdgpu_waves_per_eu(1)))
void gru_persistent(const float* __restrict__ x, const float* __restrict__ h0,
                    const float* __restrict__ Wir, const float* __restrict__ Wiz,
                    const float* __restrict__ Win, const float* __restrict__ Whr,
                    const float* __restrict__ Whz, const float* __restrict__ Whn,
                    const float* __restrict__ bhr, const float* __restrict__ bhz,
                    const float* __restrict__ bhn, const float* __restrict__ Wd,
                    const float* __restrict__ bd, float* __restrict__ out)
{
    // out layout: [carry B*H][y B*T*O]
    __shared__ float x_sh[TT * FF];                 // 16 KB
    __shared__ __align__(16) float h_sh[HH];
    __shared__ float part[3][2][HH];                // gate x half x j partials

    const int b    = blockIdx.x;
    const int tid  = threadIdx.x;
    const int g    = tid >> 8;          // 0:r 1:z 2:n   (4 waves per gate)
    const int c    = (tid >> 7) & 1;    // column half   (2 waves per half)
    const int j    = tid & (HH - 1);    // output column
    const int wv   = tid >> 6;          // wave id 0..11
    const int lane = tid & 63;
    const int c64  = c * 64;

    const float* Wh = (g == 0) ? Whr : (g == 1) ? Whz : Whn;
    const float* Wi = (g == 0) ? Wir : (g == 1) ? Wiz : Win;
    const float* bh = (g == 0) ? bhr : (g == 1) ? bhz : bhn;

    // half weight column in 64 NAMED scalar registers
    FORW(DECLW)
    {
        const float* Wcol = Wh + j;     // column j, row stride HH
        FORW(LOADW)
    }
    // pin: asm def on plain floats -> remat/demotion impossible past here
    asm volatile("" : "+v"(w_0),  "+v"(w_1),  "+v"(w_2),  "+v"(w_3),
                      "+v"(w_4),  "+v"(w_5),  "+v"(w_6),  "+v"(w_7),
                      "+v"(w_8),  "+v"(w_9),  "+v"(w_10), "+v"(w_11),
                      "+v"(w_12), "+v"(w_13), "+v"(w_14), "+v"(w_15));
    asm volatile("" : "+v"(w_16), "+v"(w_17), "+v"(w_18), "+v"(w_19),
                      "+v"(w_20), "+v"(w_21), "+v"(w_22), "+v"(w_23),
                      "+v"(w_24), "+v"(w_25), "+v"(w_26), "+v"(w_27),
                      "+v"(w_28), "+v"(w_29), "+v"(w_30), "+v"(w_31));
    asm volatile("" : "+v"(w_32), "+v"(w_33), "+v"(w_34), "+v"(w_35),
                      "+v"(w_36), "+v"(w_37), "+v"(w_38), "+v"(w_39),
                      "+v"(w_40), "+v"(w_41), "+v"(w_42), "+v"(w_43),
                      "+v"(w_44), "+v"(w_45), "+v"(w_46), "+v"(w_47));
    asm volatile("" : "+v"(w_48), "+v"(w_49), "+v"(w_50), "+v"(w_51),
                      "+v"(w_52), "+v"(w_53), "+v"(w_54), "+v"(w_55),
                      "+v"(w_56), "+v"(w_57), "+v"(w_58), "+v"(w_59),
                      "+v"(w_60), "+v"(w_61), "+v"(w_62), "+v"(w_63));

    const float gbias = (c == 0) ? bh[j] : 0.0f;
    float wi0 = 0.0f, wi1 = 0.0f;
    if (c == 0 && g != 2) { wi0 = Wi[0 * HH + j]; wi1 = Wi[1 * HH + j]; }

    // combine-thread extras (tid < 128)
    float win0 = 0.0f, win1 = 0.0f;
    if (tid < HH) { win0 = Win[0 * HH + j]; win1 = Win[1 * HH + j]; }

    // y-wave (wave 8) extras: Wd columns for this lane's two h entries
    float wdA0 = 0.f, wdA1 = 0.f, wdB0 = 0.f, wdB1 = 0.f;
    if (wv == 8) {
        wdA0 = Wd[lane * OO + 0];        wdA1 = Wd[lane * OO + 1];
        wdB0 = Wd[(lane + 64) * OO + 0]; wdB1 = Wd[(lane + 64) * OO + 1];
    }
    const float bd0 = bd[0], bd1 = bd[1];

    // stage x row (float4) and h0
    {
        const float4* xi = reinterpret_cast<const float4*>(x + (size_t)b * TT * FF);
        float4* xo = reinterpret_cast<float4*>(x_sh);
        for (int i = tid; i < TT * FF / 4; i += NT) xo[i] = xi[i];
    }
    if (tid < HH) h_sh[tid] = h0[b * HH + tid];
    __syncthreads();

    float* __restrict__ yout = out + BB * HH;

    for (int t = 0; t < TT; ++t) {
        const float x0 = x_sh[t * FF + 0];
        const float x1 = x_sh[t * FF + 1];

        // ---- phase 1: per-gate half-column GEMV (all 768 threads) ----
        float a0 = gbias + x0 * wi0 + x1 * wi1;   // wi==0 where not applicable
        float a1 = 0.f, a2 = 0.f, a3 = 0.f;
        const float4* hp = reinterpret_cast<const float4*>(h_sh + c64);
        DOTB(0,  0,  1,  2,  3)
        DOTB(1,  4,  5,  6,  7)
        DOTB(2,  8,  9,  10, 11)
        DOTB(3,  12, 13, 14, 15)
        DOTB(4,  16, 17, 18, 19)
        DOTB(5,  20, 21, 22, 23)
        DOTB(6,  24, 25, 26, 27)
        DOTB(7,  28, 29, 30, 31)
        DOTB(8,  32, 33, 34, 35)
        DOTB(9,  36, 37, 38, 39)
        DOTB(10, 40, 41, 42, 43)
        DOTB(11, 44, 45, 46, 47)
        DOTB(12, 48, 49, 50, 51)
        DOTB(13, 52, 53, 54, 55)
        DOTB(14, 56, 57, 58, 59)
        DOTB(15, 60, 61, 62, 63)
        part[g][c][j] = (a0 + a1) + (a2 + a3);

        // wave 8 additionally emits y[t-1] from h_sh (read-only in phase 1)
        if (wv == 8 && t > 0) {
            const float hv0 = h_sh[lane], hv1 = h_sh[lane + 64];
            float p0 = hv0 * wdA0 + hv1 * wdB0;
            float p1 = hv0 * wdA1 + hv1 * wdB1;
            #pragma unroll
            for (int off = 32; off >= 1; off >>= 1) {
                p0 += __shfl_xor(p0, off);
                p1 += __shfl_xor(p1, off);
            }
            if (lane == 0)
                reinterpret_cast<float2*>(yout)[(size_t)b * TT + (t - 1)] =
                    make_float2(p0 + bd0, p1 + bd1);
        }
        __syncthreads();   // barrier A: partials visible

        // ---- phase 2: combine (threads 0..127) ----
        if (tid < HH) {
            const float racc = part[0][0][j] + part[0][1][j];
            const float zacc = part[1][0][j] + part[1][1][j];
            const float macc = part[2][0][j] + part[2][1][j];
            const float r  = sigmoid_f(racc);
            const float z  = sigmoid_f(zacc);
            const float n  = tanh_f(x0 * win0 + x1 * win1 + r * macc);
            h_sh[j] = (1.0f - z) * n + z * h_sh[j];
        }
        __syncthreads();   // barrier B: h_new visible
    }

    // tail: y[T-1] and carry
    if (wv == 8) {
        const float hv0 = h_sh[lane], hv1 = h_sh[lane + 64];
        float p0 = hv0 * wdA0 + hv1 * wdB0;
        float p1 = hv0 * wdA1 + hv1 * wdB1;
        #pragma unroll
        for (int off = 32; off >= 1; off >>= 1) {
            p0 += __shfl_xor(p0, off);
            p1 += __shfl_xor(p1, off);
        }
        if (lane == 0)
            reinterpret_cast<float2*>(yout)[(size_t)b * TT + (TT - 1)] =
                make_float2(p0 + bd0, p1 + bd1);
    }
    if (tid < HH) out[b * HH + tid] = h_sh[tid];
}

extern "C" void kernel_launch(void* const* d_in, const int* in_sizes, int n_in,
                              void* d_out, int out_size, void* d_ws, size_t ws_size,
                              hipStream_t stream) {
    const float* x   = (const float*)d_in[0];
    const float* h0  = (const float*)d_in[1];
    const float* Wir = (const float*)d_in[2];
    const float* Wiz = (const float*)d_in[3];
    const float* Win = (const float*)d_in[4];
    const float* Whr = (const float*)d_in[5];
    const float* Whz = (const float*)d_in[6];
    const float* Whn = (const float*)d_in[7];
    const float* bhr = (const float*)d_in[8];
    const float* bhz = (const float*)d_in[9];
    const float* bhn = (const float*)d_in[10];
    const float* Wd  = (const float*)d_in[11];
    const float* bd  = (const float*)d_in[12];
    float* out = (float*)d_out;

    gru_persistent<<<BB, NT, 0, stream>>>(x, h0, Wir, Wiz, Win, Whr, Whz, Whn,
                                          bhr, bhz, bhn, Wd, bd, out);
}

// Round 6
// 1623.045 us; speedup vs baseline: 1.2814x; 1.2810x over previous
//
#include <hip/hip_runtime.h>
#include <math.h>

#define BB 256
#define TT 2048
#define FF 2
#define HH 128
#define OO 2
#define NT 768   // 12 waves: 3 gates x 2 column-halves x 2 waves(128 threads)

typedef _Float16 h2 __attribute__((ext_vector_type(2)));

__device__ __forceinline__ float fast_rcp(float x) { return __builtin_amdgcn_rcpf(x); }
__device__ __forceinline__ float sigmoid_f(float x) { return fast_rcp(1.0f + __expf(-x)); }
__device__ __forceinline__ float tanh_f(float x) { return 1.0f - 2.0f * fast_rcp(1.0f + __expf(2.0f * x)); }

__device__ __forceinline__ float dot2(unsigned int hv, h2 w, float acc) {
#if __has_builtin(__builtin_amdgcn_fdot2)
    return __builtin_amdgcn_fdot2(__builtin_bit_cast(h2, hv), w, acc, false);
#else
    const h2 h = __builtin_bit_cast(h2, hv);
    acc = fmaf((float)h[0], (float)w[0], acc);
    return fmaf((float)h[1], (float)w[1], acc);
#endif
}

// ---- 32 named packed-half2 weights: never an array, never address-taken ----
#define FORW32(M) \
  M(0)  M(1)  M(2)  M(3)  M(4)  M(5)  M(6)  M(7)  \
  M(8)  M(9)  M(10) M(11) M(12) M(13) M(14) M(15) \
  M(16) M(17) M(18) M(19) M(20) M(21) M(22) M(23) \
  M(24) M(25) M(26) M(27) M(28) M(29) M(30) M(31)

#define DECLW(i) h2 wp_##i;
#define LOADW(i) wp_##i[0] = (_Float16)Wcol[(c64 + 2*(i)    ) * HH]; \
                 wp_##i[1] = (_Float16)Wcol[(c64 + 2*(i) + 1) * HH];

// one uint4 LDS read = 8 halves of h -> 4 dot2 (8 MACs)
#define DOTQ(q, i0, i1, i2, i3)                       \
    {                                                 \
        const uint4 hv_ = hq[q];                      \
        a0 = dot2(hv_.x, wp_##i0, a0);                \
        a1 = dot2(hv_.y, wp_##i1, a1);                \
        a2 = dot2(hv_.z, wp_##i2, a2);                \
        a3 = dot2(hv_.w, wp_##i3, a3);                \
    }

__global__ __launch_bounds__(NT)
void gru_persistent(const float* __restrict__ x, const float* __restrict__ h0,
                    const float* __restrict__ Wir, const float* __restrict__ Wiz,
                    const float* __restrict__ Win, const float* __restrict__ Whr,
                    const float* __restrict__ Whz, const float* __restrict__ Whn,
                    const float* __restrict__ bhr, const float* __restrict__ bhz,
                    const float* __restrict__ bhn, const float* __restrict__ Wd,
                    const float* __restrict__ bd, float* __restrict__ out)
{
    // out layout: [carry B*H][y B*T*O]
    __shared__ float x_sh[TT * FF];                       // 16 KB
    __shared__ __align__(16) float    h_sh[HH];           // fp32 master h
    __shared__ __align__(16) _Float16 hh_sh[HH];          // fp16 copy for dots
    __shared__ float part[3][2][HH];                      // gate x half x j

    const int b    = blockIdx.x;
    const int tid  = threadIdx.x;
    const int g    = tid >> 8;          // 0:r 1:z 2:n   (4 waves per gate)
    const int c    = (tid >> 7) & 1;    // column half   (2 waves per half)
    const int j    = tid & (HH - 1);    // output column
    const int wv   = tid >> 6;          // wave id 0..11
    const int lane = tid & 63;
    const int c64  = c * 64;

    const float* Wh = (g == 0) ? Whr : (g == 1) ? Whz : Whn;
    const float* Wi = (g == 0) ? Wir : (g == 1) ? Wiz : Win;
    const float* bh = (g == 0) ? bhr : (g == 1) ? bhz : bhn;

    // half weight column, packed fp16: 32 VGPRs — fits the ~60-reg allocation
    FORW32(DECLW)
    {
        const float* Wcol = Wh + j;     // column j, row stride HH
        FORW32(LOADW)
    }

    const float gbias = (c == 0) ? bh[j] : 0.0f;
    float wi0 = 0.0f, wi1 = 0.0f;
    if (c == 0 && g != 2) { wi0 = Wi[0 * HH + j]; wi1 = Wi[1 * HH + j]; }

    // combine-thread extras (tid < 128)
    float win0 = 0.0f, win1 = 0.0f;
    if (tid < HH) { win0 = Win[0 * HH + j]; win1 = Win[1 * HH + j]; }

    // y-wave (wave 8) extras: Wd columns for this lane's two h entries
    float wdA0 = 0.f, wdA1 = 0.f, wdB0 = 0.f, wdB1 = 0.f;
    if (wv == 8) {
        wdA0 = Wd[lane * OO + 0];        wdA1 = Wd[lane * OO + 1];
        wdB0 = Wd[(lane + 64) * OO + 0]; wdB1 = Wd[(lane + 64) * OO + 1];
    }
    const float bd0 = bd[0], bd1 = bd[1];

    // stage x row (float4) and h0 (fp32 + fp16 copy)
    {
        const float4* xi = reinterpret_cast<const float4*>(x + (size_t)b * TT * FF);
        float4* xo = reinterpret_cast<float4*>(x_sh);
        for (int i = tid; i < TT * FF / 4; i += NT) xo[i] = xi[i];
    }
    if (tid < HH) {
        const float hv = h0[b * HH + tid];
        h_sh[tid]  = hv;
        hh_sh[tid] = (_Float16)hv;
    }
    __syncthreads();

    float* __restrict__ yout = out + BB * HH;

    for (int t = 0; t < TT; ++t) {
        const float x0 = x_sh[t * FF + 0];
        const float x1 = x_sh[t * FF + 1];

        // ---- phase 1: per-gate half-column GEMV via v_dot2_f32_f16 ----
        float a0 = gbias + x0 * wi0 + x1 * wi1;   // wi==0 where not applicable
        float a1 = 0.f, a2 = 0.f, a3 = 0.f;
        // this thread's h slice: 64 halves = 8 x uint4 (uniform across wave)
        const uint4* hq = reinterpret_cast<const uint4*>(hh_sh) + (c << 3);
        DOTQ(0,  0,  1,  2,  3)
        DOTQ(1,  4,  5,  6,  7)
        DOTQ(2,  8,  9,  10, 11)
        DOTQ(3,  12, 13, 14, 15)
        DOTQ(4,  16, 17, 18, 19)
        DOTQ(5,  20, 21, 22, 23)
        DOTQ(6,  24, 25, 26, 27)
        DOTQ(7,  28, 29, 30, 31)
        part[g][c][j] = (a0 + a1) + (a2 + a3);

        // wave 8 additionally emits y[t-1] from h_sh (read-only in phase 1)
        if (wv == 8 && t > 0) {
            const float hv0 = h_sh[lane], hv1 = h_sh[lane + 64];
            float p0 = hv0 * wdA0 + hv1 * wdB0;
            float p1 = hv0 * wdA1 + hv1 * wdB1;
            #pragma unroll
            for (int off = 32; off >= 1; off >>= 1) {
                p0 += __shfl_xor(p0, off);
                p1 += __shfl_xor(p1, off);
            }
            if (lane == 0)
                reinterpret_cast<float2*>(yout)[(size_t)b * TT + (t - 1)] =
                    make_float2(p0 + bd0, p1 + bd1);
        }
        __syncthreads();   // barrier A: partials visible

        // ---- phase 2: combine (threads 0..127), recurrence in fp32 ----
        if (tid < HH) {
            const float racc = part[0][0][j] + part[0][1][j];
            const float zacc = part[1][0][j] + part[1][1][j];
            const float macc = part[2][0][j] + part[2][1][j];
            const float r  = sigmoid_f(racc);
            const float z  = sigmoid_f(zacc);
            const float n  = tanh_f(x0 * win0 + x1 * win1 + r * macc);
            const float hn = (1.0f - z) * n + z * h_sh[j];
            h_sh[j]  = hn;
            hh_sh[j] = (_Float16)hn;
        }
        __syncthreads();   // barrier B: h_new visible
    }

    // tail: y[T-1] and carry
    if (wv == 8) {
        const float hv0 = h_sh[lane], hv1 = h_sh[lane + 64];
        float p0 = hv0 * wdA0 + hv1 * wdB0;
        float p1 = hv0 * wdA1 + hv1 * wdB1;
        #pragma unroll
        for (int off = 32; off >= 1; off >>= 1) {
            p0 += __shfl_xor(p0, off);
            p1 += __shfl_xor(p1, off);
        }
        if (lane == 0)
            reinterpret_cast<float2*>(yout)[(size_t)b * TT + (TT - 1)] =
                make_float2(p0 + bd0, p1 + bd1);
    }
    if (tid < HH) out[b * HH + tid] = h_sh[tid];
}

extern "C" void kernel_launch(void* const* d_in, const int* in_sizes, int n_in,
                              void* d_out, int out_size, void* d_ws, size_t ws_size,
                              hipStream_t stream) {
    const float* x   = (const float*)d_in[0];
    const float* h0  = (const float*)d_in[1];
    const float* Wir = (const float*)d_in[2];
    const float* Wiz = (const float*)d_in[3];
    const float* Win = (const float*)d_in[4];
    const float* Whr = (const float*)d_in[5];
    const float* Whz = (const float*)d_in[6];
    const float* Whn = (const float*)d_in[7];
    const float* bhr = (const float*)d_in[8];
    const float* bhz = (const float*)d_in[9];
    const float* bhn = (const float*)d_in[10];
    const float* Wd  = (const float*)d_in[11];
    const float* bd  = (const float*)d_in[12];
    float* out = (float*)d_out;

    gru_persistent<<<BB, NT, 0, stream>>>(x, h0, Wir, Wiz, Win, Whr, Whz, Whn,
                                          bhr, bhz, bhn, Wd, bd, out);
}